// Round 6
// baseline (3487.674 us; speedup 1.0000x reference)
//
#include <hip/hip_runtime.h>
#include <hip/hip_bf16.h>
#include <stdint.h>

#define N_TOK 8192
#define DIM   2048
#define FDIM  4096
#define NEXP  8

// ---- ws layout (bytes) ---- peak use ~252 MB; round-1 proved ws >= 311 MB
#define XB_OFF   0ull                        // bf16 x  [8192][2048]   33,554,432
#define GH_OFF   33554432ull                 // bf16 G/h [18432][4096] 150,994,944
#define META_OFF 184549376ull
#define CNT_OFF   (META_OFF)                 // int[8]
#define EBASE_OFF (META_OFF + 64ull)         // int[8]
#define ELIST_OFF (META_OFF + 128ull)        // int[8][8192]
#define EWTS_OFF  (ELIST_OFF + 262144ull)    // f32[8][8192]
#define WB_OFF   185073920ull                // bf16 weight half-buffer, 67,108,864

typedef float f32x4 __attribute__((ext_vector_type(4)));
typedef short s16x8 __attribute__((ext_vector_type(8)));

__device__ __forceinline__ uint32_t pkbf(float a, float b) {
  uint32_t ua = __builtin_bit_cast(uint32_t, a) + 0x8000u;
  uint32_t ub = __builtin_bit_cast(uint32_t, b) + 0x8000u;
  return (ua >> 16) | (ub & 0xffff0000u);
}

__device__ __forceinline__ void gld16(const void* g, void* l) {
  __builtin_amdgcn_global_load_lds(
      (__attribute__((address_space(1))) void*)g,
      (__attribute__((address_space(3))) void*)l, 16, 0, 0);
}

__global__ void zero_out_k(float* out) {
  const size_t i = ((size_t)blockIdx.x * 256 + threadIdx.x) * 4;
  *(float4*)(out + i) = make_float4(0.f, 0.f, 0.f, 0.f);
}

__global__ void init_k(int* cnt) {
  if (threadIdx.x < NEXP) cnt[threadIdx.x] = 0;
}

__global__ void router_k(const float* __restrict__ x, const float* __restrict__ gw,
                         __hip_bfloat16* __restrict__ xb, int* __restrict__ cnt,
                         int* __restrict__ elist, float* __restrict__ ewts) {
  const int n = blockIdx.x;
  const int t = threadIdx.x;
  const float* xr = x + (size_t)n * DIM;
  const float4 v0 = *(const float4*)(xr + t * 8);
  const float4 v1 = *(const float4*)(xr + t * 8 + 4);
  uint4 u;
  u.x = pkbf(v0.x, v0.y); u.y = pkbf(v0.z, v0.w);
  u.z = pkbf(v1.x, v1.y); u.w = pkbf(v1.z, v1.w);
  *(uint4*)(xb + (size_t)n * DIM + t * 8) = u;

  float p[NEXP];
#pragma unroll
  for (int e = 0; e < NEXP; ++e) {
    const float* g = gw + e * DIM + t * 8;
    const float4 g0 = *(const float4*)g;
    const float4 g1 = *(const float4*)(g + 4);
    p[e] = v0.x * g0.x + v0.y * g0.y + v0.z * g0.z + v0.w * g0.w +
           v1.x * g1.x + v1.y * g1.y + v1.z * g1.z + v1.w * g1.w;
  }
#pragma unroll
  for (int off = 32; off >= 1; off >>= 1)
#pragma unroll
    for (int e = 0; e < NEXP; ++e) p[e] += __shfl_xor(p[e], off, 64);

  __shared__ float red[4][NEXP];
  const int lane = t & 63, wv = t >> 6;
  if (lane == 0) {
#pragma unroll
    for (int e = 0; e < NEXP; ++e) red[wv][e] = p[e];
  }
  __syncthreads();
  if (t == 0) {
    float l0 = -1e30f, l1 = -1e30f;
    int e0 = 0, e1 = 0;
#pragma unroll
    for (int e = 0; e < NEXP; ++e) {
      float v = red[0][e] + red[1][e] + red[2][e] + red[3][e];
      if (v > l0) { l1 = l0; e1 = e0; l0 = v; e0 = e; }
      else if (v > l1) { l1 = v; e1 = e; }
    }
    const float ed = expf(l1 - l0);
    const float inv = 1.f / (1.f + ed);
    int s0 = atomicAdd(cnt + e0, 1);
    elist[e0 * N_TOK + s0] = n;
    ewts[e0 * N_TOK + s0] = inv;
    int s1 = atomicAdd(cnt + e1, 1);
    elist[e1 * N_TOK + s1] = (int)((uint32_t)n | 0x80000000u);
    ewts[e1 * N_TOK + s1] = ed * inv;
  }
}

__global__ void scan_k(const int* __restrict__ cnt, int* __restrict__ ebase) {
  if (threadIdx.x == 0 && blockIdx.x == 0) {
    int b = 0;
    for (int e = 0; e < NEXP; ++e) { ebase[e] = b; b += (cnt[e] + 255) & ~255; }
  }
}

// convert rows [r0, r0+nrh) of each expert's [rtot][kd] fp32 matrix -> bf16 [e][nrh][kd]
__global__ void convW_k(const float* __restrict__ src, __hip_bfloat16* __restrict__ dst,
                        int r0, int nrh, int rtot, int kd) {
  const int cpr = kd / 8;
  const int total = NEXP * nrh * cpr;
  for (int i = blockIdx.x * blockDim.x + threadIdx.x; i < total;
       i += gridDim.x * blockDim.x) {
    const int e = i / (nrh * cpr);
    const int rem = i - e * nrh * cpr;
    const int lr = rem / cpr;
    const int c = rem - lr * cpr;
    const float* s = src + ((size_t)e * rtot + r0 + lr) * (size_t)kd + c * 8;
    const float4 a = *(const float4*)s;
    const float4 b = *(const float4*)(s + 4);
    uint4 u;
    u.x = pkbf(a.x, a.y); u.y = pkbf(a.z, a.w);
    u.z = pkbf(b.x, b.y); u.w = pkbf(b.z, b.w);
    *(uint4*)(dst + ((size_t)e * nrh + lr) * (size_t)kd + c * 8) = u;
  }
}

// ============================================================================
// 256x256 grouped GEMM, BK=64, 8 waves (2M x 4N), 4 phases/K-tile with
// COUNTED vmcnt(4) (never 0 in the loop).
// LDS per dbuf 64KB: A planes kh=0,1 at kh*16384 ([256 rows][4 slots of 16B]),
// B planes at 32768 + kh*16384. 2 dbufs = 128KB.
// Regions are K-half planes; consumption is phase-ordered (p0/p1 use k0,
// p2/p3 use k1), staging of tile t+1: p0->A-k0, p1->B-k0, p2->A-k1, p3->B-k1;
// vmcnt(4) before end-of-p1 and end-of-p3 barriers publishes exactly the
// regions needed 1 phase later. 4 loads always in flight.
// Swizzle (both sides): plane row r slot s holds src granule s^(r&3)^((r>>2)&3).
// MODE 0: G = Xb@w1h^T -> Gh ; MODE 1: h = silu(Gh)*(Xb@w3h^T) -> Gh ;
// MODE 2: out += we * (h@w2h^T)  (atomicAdd, 2 commutative adds/elem).
// ============================================================================
template <int KD, int MODE>
__global__ __launch_bounds__(512, 2) void gemm256(
    const __hip_bfloat16* __restrict__ Asrc, const __hip_bfloat16* __restrict__ Bw,
    __hip_bfloat16* __restrict__ Gh, float* __restrict__ out,
    const int* __restrict__ cnt, const int* __restrict__ ebase,
    const int* __restrict__ elist, const float* __restrict__ ewts, int noff) {
  constexpr int NT = KD / 64;
  constexpr int NRH = (MODE == 2 ? 1024 : 2048);   // B rows per expert in half-buffer
  const int e = blockIdx.z;
  const int count = cnt[e];
  const int mt = blockIdx.x;
  if (mt * 256 >= count) return;
  const int n0 = noff + blockIdx.y * 256;

  __shared__ char lds[131072];
  const int tid = threadIdx.x;
  const int lane = tid & 63, wv = tid >> 6;
  const int wr = wv >> 2, wc = wv & 3;
  const int* lst = elist + e * N_TOK;
  const size_t hrow0 = (size_t)ebase[e] + (size_t)mt * 256;

  // ---- staging precompute: thread covers (row=tid>>2 + i*128, slot=tid&3)
  const int sr = tid >> 2, ss = tid & 3;
  const int sw = ((sr & 3) ^ ((sr >> 2) & 3));    // swz(r), same for i=0,1
  const int gsrc = ss ^ sw;                        // source granule (pre-swizzled)
  size_t srcA[2], srcB[2];
#pragma unroll
  for (int i = 0; i < 2; ++i) {
    const int r = sr + i * 128;
    size_t ga;
    if (MODE == 2) {
      ga = hrow0 + r;
    } else {
      int idx = mt * 256 + r;
      if (idx >= count) idx = 0;
      ga = (size_t)(lst[idx] & 0x7fffffff);
    }
    srcA[i] = ga * (size_t)KD + gsrc * 8;
    srcB[i] = ((size_t)e * NRH + (n0 - noff) + r) * (size_t)KD + gsrc * 8;
  }
  const int ldsW = wv * 1024;                      // + lane*16 applied by HW

  // ---- fragment read offsets (swizzle term is a per-lane constant)
  const int frcol = (lane & 15) * 64 +
                    (((lane >> 4) ^ ((lane & 3) ^ ((lane >> 2) & 3))) << 4);
  const int ardb = wr * 8192;          // A: + kh*16384 + (mb+s)*1024 + frcol
  const int brdb = 32768 + wc * 4096;  // B: + kh*16384 + n*1024 + frcol

  f32x4 acc[8][4];
#pragma unroll
  for (int m = 0; m < 8; ++m)
#pragma unroll
    for (int n = 0; n < 4; ++n) acc[m][n] = {0.f, 0.f, 0.f, 0.f};
  s16x8 Afr[4], Bfr[4];

  auto stA = [&](int tt, int db, int kh) {
#pragma unroll
    for (int i = 0; i < 2; ++i)
      gld16(Asrc + srcA[i] + (size_t)tt * 64 + kh * 32,
            lds + db * 65536 + kh * 16384 + i * 8192 + ldsW);
  };
  auto stB = [&](int tt, int db, int kh) {
#pragma unroll
    for (int i = 0; i < 2; ++i)
      gld16(Bw + srcB[i] + (size_t)tt * 64 + kh * 32,
            lds + db * 65536 + 32768 + kh * 16384 + i * 8192 + ldsW);
  };
  auto rdA = [&](int db, int mb, int kh) {
#pragma unroll
    for (int s = 0; s < 4; ++s)
      Afr[s] = *(const s16x8*)(lds + db * 65536 + kh * 16384 + ardb +
                               (mb + s) * 1024 + frcol);
  };
  auto rdB = [&](int db, int kh) {
#pragma unroll
    for (int n = 0; n < 4; ++n)
      Bfr[n] = *(const s16x8*)(lds + db * 65536 + kh * 16384 + brdb +
                               n * 1024 + frcol);
  };

#define PH_PRE()                                            \
  __builtin_amdgcn_sched_barrier(0);                        \
  __builtin_amdgcn_s_barrier();                             \
  __builtin_amdgcn_sched_barrier(0);                        \
  asm volatile("s_waitcnt lgkmcnt(0)" ::: "memory");        \
  __builtin_amdgcn_sched_barrier(0);                        \
  __builtin_amdgcn_s_setprio(1);

#define PH_POST_PLAIN()                                     \
  __builtin_amdgcn_s_setprio(0);                            \
  __builtin_amdgcn_sched_barrier(0);                        \
  __builtin_amdgcn_s_barrier();                             \
  __builtin_amdgcn_sched_barrier(0);

#define PH_POST_VM4()                                       \
  __builtin_amdgcn_s_setprio(0);                            \
  __builtin_amdgcn_sched_barrier(0);                        \
  asm volatile("s_waitcnt vmcnt(4)" ::: "memory");          \
  __builtin_amdgcn_sched_barrier(0);                        \
  __builtin_amdgcn_s_barrier();                             \
  __builtin_amdgcn_sched_barrier(0);

#define MFMA16(MB)                                                        \
  _Pragma("unroll") for (int s = 0; s < 4; ++s)                           \
  _Pragma("unroll") for (int n = 0; n < 4; ++n)                           \
    acc[(MB) + s][n] = __builtin_amdgcn_mfma_f32_16x16x32_bf16(           \
        Afr[s], Bfr[n], acc[(MB) + s][n], 0, 0, 0);

  // ---- prologue: stage tile 0 fully into buf 0, drain, publish
  stA(0, 0, 0); stB(0, 0, 0); stA(0, 0, 1); stB(0, 0, 1);
  asm volatile("s_waitcnt vmcnt(0)" ::: "memory");
  __builtin_amdgcn_sched_barrier(0);
  __builtin_amdgcn_s_barrier();
  __builtin_amdgcn_sched_barrier(0);

  for (int t = 0; t < NT; ++t) {
    const int nb = t & 1;
    const int tn = (t + 1 < NT) ? t + 1 : NT - 1;  // clamp keeps counts uniform
    // p0: consume k0 (B + A m0-3); stage A-k0(t+1)
    rdB(nb, 0); rdA(nb, 0, 0);
    stA(tn, nb ^ 1, 0);
    PH_PRE(); MFMA16(0); PH_POST_PLAIN();
    // p1: consume k0 (A m4-7); stage B-k0(t+1); vmcnt(4) publishes k1(t)
    rdA(nb, 4, 0);
    stB(tn, nb ^ 1, 0);
    PH_PRE(); MFMA16(4); PH_POST_VM4();
    // p2: consume k1 (B + A m0-3); stage A-k1(t+1)
    rdB(nb, 1); rdA(nb, 0, 1);
    stA(tn, nb ^ 1, 1);
    PH_PRE(); MFMA16(0); PH_POST_PLAIN();
    // p3: consume k1 (A m4-7); stage B-k1(t+1); vmcnt(4) publishes k0(t+1)
    rdA(nb, 4, 1);
    stB(tn, nb ^ 1, 1);
    PH_PRE(); MFMA16(4); PH_POST_VM4();
  }
  asm volatile("s_waitcnt vmcnt(0)" ::: "memory");

  // ---- epilogue
  const int erow = (lane >> 4) * 4;
  const int ecol = lane & 15;
  if constexpr (MODE == 0) {
#pragma unroll
    for (int m = 0; m < 8; ++m)
#pragma unroll
      for (int n = 0; n < 4; ++n) {
        const size_t cb = n0 + wc * 64 + n * 16 + ecol;
#pragma unroll
        for (int j = 0; j < 4; ++j) {
          const size_t r = hrow0 + wr * 128 + m * 16 + erow + j;
          Gh[r * FDIM + cb] = __float2bfloat16(acc[m][n][j]);
        }
      }
  } else if constexpr (MODE == 1) {
#pragma unroll
    for (int m = 0; m < 8; ++m)
#pragma unroll
      for (int n = 0; n < 4; ++n) {
        const size_t cb = n0 + wc * 64 + n * 16 + ecol;
#pragma unroll
        for (int j = 0; j < 4; ++j) {
          const size_t r = hrow0 + wr * 128 + m * 16 + erow + j;
          const float g = __bfloat162float(Gh[r * FDIM + cb]);
          const float hv = g / (1.f + __expf(-g)) * acc[m][n][j];
          Gh[r * FDIM + cb] = __float2bfloat16(hv);
        }
      }
  } else {
#pragma unroll
    for (int m = 0; m < 8; ++m)
#pragma unroll
      for (int j = 0; j < 4; ++j) {
        const int i = mt * 256 + wr * 128 + m * 16 + erow + j;
        if (i < count) {
          const uint32_t info = (uint32_t)lst[i];
          const int tok = (int)(info & 0x7fffffffu);
          const float wt = ewts[e * N_TOK + i];
          float* prow = out + (size_t)tok * DIM;
#pragma unroll
          for (int n = 0; n < 4; ++n) {
            const int cb = n0 + wc * 64 + n * 16 + ecol;
            atomicAdd(prow + cb, wt * acc[m][n][j]);
          }
        }
      }
  }
}

extern "C" void kernel_launch(void* const* d_in, const int* in_sizes, int n_in,
                              void* d_out, int out_size, void* d_ws, size_t ws_size,
                              hipStream_t stream) {
  const float* stm = (const float*)d_in[0];
  const float* gw = (const float*)d_in[1];
  const float* w1 = (const float*)d_in[2];
  const float* w2 = (const float*)d_in[3];
  const float* w3 = (const float*)d_in[4];
  float* out = (float*)d_out;
  char* ws = (char*)d_ws;

  __hip_bfloat16* xb = (__hip_bfloat16*)(ws + XB_OFF);
  __hip_bfloat16* Gh = (__hip_bfloat16*)(ws + GH_OFF);
  int* cnt = (int*)(ws + CNT_OFF);
  int* ebase = (int*)(ws + EBASE_OFF);
  int* elist = (int*)(ws + ELIST_OFF);
  float* ewts = (float*)(ws + EWTS_OFF);
  __hip_bfloat16* wb = (__hip_bfloat16*)(ws + WB_OFF);

  zero_out_k<<<N_TOK * DIM / 1024, 256, 0, stream>>>(out);
  init_k<<<1, 64, 0, stream>>>(cnt);
  router_k<<<N_TOK, 256, 0, stream>>>(stm, gw, xb, cnt, elist, ewts);
  scan_k<<<1, 64, 0, stream>>>(cnt, ebase);

  const dim3 gUp(32, 8, 8);   // (Mtiles, panels/half, experts)
  const dim3 gDn(32, 4, 8);

  // gate GEMM (w1), two F-halves
  convW_k<<<2048, 256, 0, stream>>>(w1, wb, 0, 2048, FDIM, DIM);
  gemm256<DIM, 0><<<gUp, 512, 0, stream>>>(xb, wb, Gh, out, cnt, ebase, elist, ewts, 0);
  convW_k<<<2048, 256, 0, stream>>>(w1, wb, 2048, 2048, FDIM, DIM);
  gemm256<DIM, 0><<<gUp, 512, 0, stream>>>(xb, wb, Gh, out, cnt, ebase, elist, ewts, 2048);

  // up GEMM (w3) + silu*mul, two F-halves
  convW_k<<<2048, 256, 0, stream>>>(w3, wb, 0, 2048, FDIM, DIM);
  gemm256<DIM, 1><<<gUp, 512, 0, stream>>>(xb, wb, Gh, out, cnt, ebase, elist, ewts, 0);
  convW_k<<<2048, 256, 0, stream>>>(w3, wb, 2048, 2048, FDIM, DIM);
  gemm256<DIM, 1><<<gUp, 512, 0, stream>>>(xb, wb, Gh, out, cnt, ebase, elist, ewts, 2048);

  // down GEMM (w2), two D-halves
  convW_k<<<2048, 256, 0, stream>>>(w2, wb, 0, 1024, DIM, FDIM);
  gemm256<FDIM, 2><<<gDn, 512, 0, stream>>>(Gh, wb, Gh, out, cnt, ebase, elist, ewts, 0);
  convW_k<<<2048, 256, 0, stream>>>(w2, wb, 1024, 1024, DIM, FDIM);
  gemm256<FDIM, 2><<<gDn, 512, 0, stream>>>(Gh, wb, Gh, out, cnt, ebase, elist, ewts, 1024);
}

// Round 7
// 3160.029 us; speedup vs baseline: 1.1037x; 1.1037x over previous
//
#include <hip/hip_runtime.h>
#include <hip/hip_bf16.h>
#include <stdint.h>

#define N_TOK 8192
#define DIM   2048
#define FDIM  4096
#define NEXP  8

// ---- ws layout (bytes) ---- peak use ~252 MB; round-1 proved ws >= 311 MB
#define XB_OFF   0ull                        // bf16 x  [8192][2048]   33,554,432
#define GH_OFF   33554432ull                 // bf16 G/h [18432][4096] 150,994,944
#define META_OFF 184549376ull
#define CNT_OFF   (META_OFF)                 // int[8]
#define EBASE_OFF (META_OFF + 64ull)         // int[8]
#define ELIST_OFF (META_OFF + 128ull)        // int[8][8192]
#define EWTS_OFF  (ELIST_OFF + 262144ull)    // f32[8][8192]
#define WB_OFF   185073920ull                // bf16 weight half-buffer, 67,108,864

typedef float f32x4 __attribute__((ext_vector_type(4)));
typedef short s16x8 __attribute__((ext_vector_type(8)));

__device__ __forceinline__ uint32_t pkbf(float a, float b) {
  uint32_t ua = __builtin_bit_cast(uint32_t, a) + 0x8000u;
  uint32_t ub = __builtin_bit_cast(uint32_t, b) + 0x8000u;
  return (ua >> 16) | (ub & 0xffff0000u);
}

__device__ __forceinline__ void gld16(const void* g, void* l) {
  __builtin_amdgcn_global_load_lds(
      (__attribute__((address_space(1))) void*)g,
      (__attribute__((address_space(3))) void*)l, 16, 0, 0);
}

__global__ void zero_out_k(float* out) {
  const size_t i = ((size_t)blockIdx.x * 256 + threadIdx.x) * 4;
  *(float4*)(out + i) = make_float4(0.f, 0.f, 0.f, 0.f);
}

__global__ void init_k(int* cnt) {
  if (threadIdx.x < NEXP) cnt[threadIdx.x] = 0;
}

__global__ void router_k(const float* __restrict__ x, const float* __restrict__ gw,
                         __hip_bfloat16* __restrict__ xb, int* __restrict__ cnt,
                         int* __restrict__ elist, float* __restrict__ ewts) {
  const int n = blockIdx.x;
  const int t = threadIdx.x;
  const float* xr = x + (size_t)n * DIM;
  const float4 v0 = *(const float4*)(xr + t * 8);
  const float4 v1 = *(const float4*)(xr + t * 8 + 4);
  uint4 u;
  u.x = pkbf(v0.x, v0.y); u.y = pkbf(v0.z, v0.w);
  u.z = pkbf(v1.x, v1.y); u.w = pkbf(v1.z, v1.w);
  *(uint4*)(xb + (size_t)n * DIM + t * 8) = u;

  float p[NEXP];
#pragma unroll
  for (int e = 0; e < NEXP; ++e) {
    const float* g = gw + e * DIM + t * 8;
    const float4 g0 = *(const float4*)g;
    const float4 g1 = *(const float4*)(g + 4);
    p[e] = v0.x * g0.x + v0.y * g0.y + v0.z * g0.z + v0.w * g0.w +
           v1.x * g1.x + v1.y * g1.y + v1.z * g1.z + v1.w * g1.w;
  }
#pragma unroll
  for (int off = 32; off >= 1; off >>= 1)
#pragma unroll
    for (int e = 0; e < NEXP; ++e) p[e] += __shfl_xor(p[e], off, 64);

  __shared__ float red[4][NEXP];
  const int lane = t & 63, wv = t >> 6;
  if (lane == 0) {
#pragma unroll
    for (int e = 0; e < NEXP; ++e) red[wv][e] = p[e];
  }
  __syncthreads();
  if (t == 0) {
    float l0 = -1e30f, l1 = -1e30f;
    int e0 = 0, e1 = 0;
#pragma unroll
    for (int e = 0; e < NEXP; ++e) {
      float v = red[0][e] + red[1][e] + red[2][e] + red[3][e];
      if (v > l0) { l1 = l0; e1 = e0; l0 = v; e0 = e; }
      else if (v > l1) { l1 = v; e1 = e; }
    }
    const float ed = expf(l1 - l0);
    const float inv = 1.f / (1.f + ed);
    int s0 = atomicAdd(cnt + e0, 1);
    elist[e0 * N_TOK + s0] = n;
    ewts[e0 * N_TOK + s0] = inv;
    int s1 = atomicAdd(cnt + e1, 1);
    elist[e1 * N_TOK + s1] = (int)((uint32_t)n | 0x80000000u);
    ewts[e1 * N_TOK + s1] = ed * inv;
  }
}

__global__ void scan_k(const int* __restrict__ cnt, int* __restrict__ ebase) {
  if (threadIdx.x == 0 && blockIdx.x == 0) {
    int b = 0;
    for (int e = 0; e < NEXP; ++e) { ebase[e] = b; b += (cnt[e] + 255) & ~255; }
  }
}

// convert rows [r0, r0+nrh) of each expert's [rtot][kd] fp32 matrix -> bf16 [e][nrh][kd]
__global__ void convW_k(const float* __restrict__ src, __hip_bfloat16* __restrict__ dst,
                        int r0, int nrh, int rtot, int kd) {
  const int cpr = kd / 8;
  const int total = NEXP * nrh * cpr;
  for (int i = blockIdx.x * blockDim.x + threadIdx.x; i < total;
       i += gridDim.x * blockDim.x) {
    const int e = i / (nrh * cpr);
    const int rem = i - e * nrh * cpr;
    const int lr = rem / cpr;
    const int c = rem - lr * cpr;
    const float* s = src + ((size_t)e * rtot + r0 + lr) * (size_t)kd + c * 8;
    const float4 a = *(const float4*)s;
    const float4 b = *(const float4*)(s + 4);
    uint4 u;
    u.x = pkbf(a.x, a.y); u.y = pkbf(a.z, a.w);
    u.z = pkbf(b.x, b.y); u.w = pkbf(b.z, b.w);
    *(uint4*)(dst + ((size_t)e * nrh + lr) * (size_t)kd + c * 8) = u;
  }
}

// ============================================================================
// 256x256 grouped GEMM, BK=64, 8 waves, 4 phases/K-tile, m201-style rotation:
// K-split LDS regions per buffer: Ak0@0, Ak1@16K, Bk0@32K, Bk1@48K, each
// [256 rows][4 slots x 16B]; 2 buffers = 128KB. Region rewritten 2 tiles
// ahead, one phase after its last read:
//   p0: read {Bk0,Ak0.G0}, stage Ak1(t+1)->buf^1
//   p1: read {Ak0.G1},     stage Bk0(t+2)->buf,   vmcnt(10)
//   p2: read {Bk1,Ak1.G0}, stage Ak0(t+2)->buf
//   p3: read {Ak1.G1},     stage Bk1(t+2)->buf,   vmcnt(10)
// FIFO trace: each region published 1-2 phases before first read, 5-6 phase
// latency budget, 10-14 loads always in flight, never drained to 0.
// Swizzle (both sides): slot' = slot ^ ((row>>1)&3); read-side XOR is a
// per-lane constant (8-lane-chunk bijective -> conflict-free).
// MODE 0: G = Xb@w1h^T -> Gh ; MODE 1: h = silu(Gh)*(Xb@w3h^T) -> Gh ;
// MODE 2: out += we * (h@w2h^T)  (atomicAdd, 2 commutative adds/elem).
// ============================================================================
template <int KD, int MODE>
__global__ __launch_bounds__(512, 2) void gemm256(
    const __hip_bfloat16* __restrict__ Asrc, const __hip_bfloat16* __restrict__ Bw,
    __hip_bfloat16* __restrict__ Gh, float* __restrict__ out,
    const int* __restrict__ cnt, const int* __restrict__ ebase,
    const int* __restrict__ elist, const float* __restrict__ ewts, int noff) {
  constexpr int NT = KD / 64;
  constexpr int NRH = (MODE == 2 ? 1024 : 2048);
  const int e = blockIdx.z;
  const int count = cnt[e];
  const int mt = blockIdx.x;
  if (mt * 256 >= count) return;
  const int n0 = noff + blockIdx.y * 256;

  __shared__ char lds[131072];
  const int tid = threadIdx.x;
  const int lane = tid & 63, wv = tid >> 6;
  const int wr = wv >> 2, wc = wv & 3;
  const int* lst = elist + e * N_TOK;
  const size_t hrow0 = (size_t)ebase[e] + (size_t)mt * 256;

  // ---- staging: thread covers (row = tid>>2 (+128), slot = tid&3) of a region
  const int sr = tid >> 2;
  const int gsrc = (tid & 3) ^ ((sr >> 1) & 3);   // pre-swizzled source granule
  size_t srcA[2], srcB[2];
#pragma unroll
  for (int i = 0; i < 2; ++i) {
    const int r = sr + i * 128;
    size_t ga;
    if (MODE == 2) {
      ga = hrow0 + r;
    } else {
      int idx = mt * 256 + r;
      if (idx >= count) idx = 0;
      ga = (size_t)(lst[idx] & 0x7fffffff);
    }
    srcA[i] = ga * (size_t)KD + gsrc * 8;
    srcB[i] = ((size_t)e * NRH + (n0 - noff) + r) * (size_t)KD + gsrc * 8;
  }
  const int ldsW = wv * 1024;                     // + lane*16 applied by HW

  // ---- fragment reads: row = base + (lane&15), k-granule q = lane>>4
  //      swizzle XOR collapses to a per-lane constant
  const int frcol = (lane & 15) * 64 +
                    (((lane >> 4) ^ (((lane & 15) >> 1) & 3)) << 4);

  f32x4 acc[8][4];
#pragma unroll
  for (int m = 0; m < 8; ++m)
#pragma unroll
    for (int n = 0; n < 4; ++n) acc[m][n] = {0.f, 0.f, 0.f, 0.f};
  s16x8 Afr[4], Bfr[4];

  auto stageA = [&](int kk, int tt, int db) {
#pragma unroll
    for (int i = 0; i < 2; ++i)
      gld16(Asrc + srcA[i] + tt * 64 + kk * 32,
            lds + db * 65536 + kk * 16384 + i * 8192 + ldsW);
  };
  auto stageB = [&](int kk, int tt, int db) {
#pragma unroll
    for (int i = 0; i < 2; ++i)
      gld16(Bw + srcB[i] + tt * 64 + kk * 32,
            lds + db * 65536 + 32768 + kk * 16384 + i * 8192 + ldsW);
  };
  auto rdA = [&](int db, int mb, int kk) {
#pragma unroll
    for (int s = 0; s < 4; ++s)
      Afr[s] = *(const s16x8*)(lds + db * 65536 + kk * 16384 + wr * 8192 +
                               (mb + s) * 1024 + frcol);
  };
  auto rdB = [&](int db, int kk) {
#pragma unroll
    for (int n = 0; n < 4; ++n)
      Bfr[n] = *(const s16x8*)(lds + db * 65536 + 32768 + kk * 16384 +
                               wc * 4096 + n * 1024 + frcol);
  };

#define PH_PRE()                                            \
  __builtin_amdgcn_sched_barrier(0);                        \
  __builtin_amdgcn_s_barrier();                             \
  __builtin_amdgcn_sched_barrier(0);                        \
  asm volatile("s_waitcnt lgkmcnt(0)" ::: "memory");        \
  __builtin_amdgcn_sched_barrier(0);                        \
  __builtin_amdgcn_s_setprio(1);

#define PH_POST_PLAIN()                                     \
  __builtin_amdgcn_s_setprio(0);                            \
  __builtin_amdgcn_sched_barrier(0);                        \
  __builtin_amdgcn_s_barrier();                             \
  __builtin_amdgcn_sched_barrier(0);

#define PH_POST_VM()                                        \
  __builtin_amdgcn_s_setprio(0);                            \
  __builtin_amdgcn_sched_barrier(0);                        \
  asm volatile("s_waitcnt vmcnt(10)" ::: "memory");         \
  __builtin_amdgcn_sched_barrier(0);                        \
  __builtin_amdgcn_s_barrier();                             \
  __builtin_amdgcn_sched_barrier(0);

#define MFMA16(MB)                                                        \
  _Pragma("unroll") for (int s = 0; s < 4; ++s)                           \
  _Pragma("unroll") for (int n = 0; n < 4; ++n)                           \
    acc[(MB) + s][n] = __builtin_amdgcn_mfma_f32_16x16x32_bf16(           \
        Afr[s], Bfr[n], acc[(MB) + s][n], 0, 0, 0);

  // ---- prologue (FIFO): tile0 {Bk0,Ak0,Bk1,Ak1}->buf0; tile1 {Bk0,Ak0,Bk1}->buf1
  stageB(0, 0, 0); stageA(0, 0, 0); stageB(1, 0, 0); stageA(1, 0, 0);
  stageB(0, 1, 1); stageA(0, 1, 1); stageB(1, 1, 1);
  asm volatile("s_waitcnt vmcnt(6)" ::: "memory");   // publish tile0, keep 3 halves
  __builtin_amdgcn_sched_barrier(0);
  __builtin_amdgcn_s_barrier();
  __builtin_amdgcn_sched_barrier(0);

#pragma unroll 2
  for (int t = 0; t < NT; ++t) {
    const int cb = t & 1;
    const int t1 = (t + 1 < NT) ? t + 1 : NT - 1;  // clamp: redundant tail stages
    const int t2 = (t + 2 < NT) ? t + 2 : NT - 1;  // (write dead regions only)
    // p0: consume Bk0 + Ak0.G0; stage Ak1(t+1) -> other buffer
    rdB(cb, 0); rdA(cb, 0, 0);
    stageA(1, t1, cb ^ 1);
    PH_PRE(); MFMA16(0); PH_POST_PLAIN();
    // p1: consume Ak0.G1; stage Bk0(t+2) -> current buffer
    rdA(cb, 4, 0);
    stageB(0, t2, cb);
    PH_PRE(); MFMA16(4); PH_POST_VM();
    // p2: consume Bk1 + Ak1.G0; stage Ak0(t+2)
    rdB(cb, 1); rdA(cb, 0, 1);
    stageA(0, t2, cb);
    PH_PRE(); MFMA16(0); PH_POST_PLAIN();
    // p3: consume Ak1.G1; stage Bk1(t+2)
    rdA(cb, 4, 1);
    stageB(1, t2, cb);
    PH_PRE(); MFMA16(4); PH_POST_VM();
  }

  // ---- epilogue (no LDS use; outstanding loads target dead regions)
  const int erow = (lane >> 4) * 4;
  const int ecol = lane & 15;
  if constexpr (MODE == 0) {
#pragma unroll
    for (int m = 0; m < 8; ++m)
#pragma unroll
      for (int n = 0; n < 4; ++n) {
        const size_t cb2 = n0 + wc * 64 + n * 16 + ecol;
#pragma unroll
        for (int j = 0; j < 4; ++j) {
          const size_t r = hrow0 + wr * 128 + m * 16 + erow + j;
          Gh[r * FDIM + cb2] = __float2bfloat16(acc[m][n][j]);
        }
      }
  } else if constexpr (MODE == 1) {
#pragma unroll
    for (int m = 0; m < 8; ++m)
#pragma unroll
      for (int n = 0; n < 4; ++n) {
        const size_t cb2 = n0 + wc * 64 + n * 16 + ecol;
#pragma unroll
        for (int j = 0; j < 4; ++j) {
          const size_t r = hrow0 + wr * 128 + m * 16 + erow + j;
          const float g = __bfloat162float(Gh[r * FDIM + cb2]);
          const float hv = g / (1.f + __expf(-g)) * acc[m][n][j];
          Gh[r * FDIM + cb2] = __float2bfloat16(hv);
        }
      }
  } else {
#pragma unroll
    for (int m = 0; m < 8; ++m)
#pragma unroll
      for (int j = 0; j < 4; ++j) {
        const int i = mt * 256 + wr * 128 + m * 16 + erow + j;
        if (i < count) {
          const uint32_t info = (uint32_t)lst[i];
          const int tok = (int)(info & 0x7fffffffu);
          const float wt = ewts[e * N_TOK + i];
          float* prow = out + (size_t)tok * DIM;
#pragma unroll
          for (int n = 0; n < 4; ++n) {
            const int cb2 = n0 + wc * 64 + n * 16 + ecol;
            atomicAdd(prow + cb2, wt * acc[m][n][j]);
          }
        }
      }
  }
}

extern "C" void kernel_launch(void* const* d_in, const int* in_sizes, int n_in,
                              void* d_out, int out_size, void* d_ws, size_t ws_size,
                              hipStream_t stream) {
  const float* stm = (const float*)d_in[0];
  const float* gw = (const float*)d_in[1];
  const float* w1 = (const float*)d_in[2];
  const float* w2 = (const float*)d_in[3];
  const float* w3 = (const float*)d_in[4];
  float* out = (float*)d_out;
  char* ws = (char*)d_ws;

  __hip_bfloat16* xb = (__hip_bfloat16*)(ws + XB_OFF);
  __hip_bfloat16* Gh = (__hip_bfloat16*)(ws + GH_OFF);
  int* cnt = (int*)(ws + CNT_OFF);
  int* ebase = (int*)(ws + EBASE_OFF);
  int* elist = (int*)(ws + ELIST_OFF);
  float* ewts = (float*)(ws + EWTS_OFF);
  __hip_bfloat16* wb = (__hip_bfloat16*)(ws + WB_OFF);

  zero_out_k<<<N_TOK * DIM / 1024, 256, 0, stream>>>(out);
  init_k<<<1, 64, 0, stream>>>(cnt);
  router_k<<<N_TOK, 256, 0, stream>>>(stm, gw, xb, cnt, elist, ewts);
  scan_k<<<1, 64, 0, stream>>>(cnt, ebase);

  const dim3 gUp(32, 8, 8);   // (Mtiles, panels/half, experts)
  const dim3 gDn(32, 4, 8);

  // gate GEMM (w1), two F-halves
  convW_k<<<2048, 256, 0, stream>>>(w1, wb, 0, 2048, FDIM, DIM);
  gemm256<DIM, 0><<<gUp, 512, 0, stream>>>(xb, wb, Gh, out, cnt, ebase, elist, ewts, 0);
  convW_k<<<2048, 256, 0, stream>>>(w1, wb, 2048, 2048, FDIM, DIM);
  gemm256<DIM, 0><<<gUp, 512, 0, stream>>>(xb, wb, Gh, out, cnt, ebase, elist, ewts, 2048);

  // up GEMM (w3) + silu*mul, two F-halves
  convW_k<<<2048, 256, 0, stream>>>(w3, wb, 0, 2048, FDIM, DIM);
  gemm256<DIM, 1><<<gUp, 512, 0, stream>>>(xb, wb, Gh, out, cnt, ebase, elist, ewts, 0);
  convW_k<<<2048, 256, 0, stream>>>(w3, wb, 2048, 2048, FDIM, DIM);
  gemm256<DIM, 1><<<gUp, 512, 0, stream>>>(xb, wb, Gh, out, cnt, ebase, elist, ewts, 2048);

  // down GEMM (w2), two D-halves
  convW_k<<<2048, 256, 0, stream>>>(w2, wb, 0, 1024, DIM, FDIM);
  gemm256<FDIM, 2><<<gDn, 512, 0, stream>>>(Gh, wb, Gh, out, cnt, ebase, elist, ewts, 0);
  convW_k<<<2048, 256, 0, stream>>>(w2, wb, 1024, 1024, DIM, FDIM);
  gemm256<FDIM, 2><<<gDn, 512, 0, stream>>>(Gh, wb, Gh, out, cnt, ebase, elist, ewts, 1024);
}